// Round 2
// baseline (2052.041 us; speedup 1.0000x reference)
//
#include <hip/hip_runtime.h>
#include <stdint.h>

#define B_ 4
#define N_TOK 1024
#define DM 256
#define DEPTH 12
#define DSTATE 16
#define DIN 512
#define LVIS 768
#define MROWS (B_ * LVIS)  // 3072
#define NCHUNK 32
#define CLEN 24            // 768 / 32
#define EPS_F 1e-5f

// ---------- helpers ----------
__device__ __forceinline__ float bs2f(uint32_t u) {
  uint32_t x = (u & 0xffffu) << 16;
  float f; __builtin_memcpy(&f, &x, 4); return f;
}
__device__ __forceinline__ uint16_t f2b(float f) {
  uint32_t u; __builtin_memcpy(&u, &f, 4);
  return (uint16_t)((u + 0x7fffu + ((u >> 16) & 1u)) >> 16);
}
__device__ __forceinline__ float silu_f(float x) { return x / (1.f + __expf(-x)); }
__device__ __forceinline__ float block_sum256(float v, volatile float* scr) {
  int t = threadIdx.x, lane = t & 63, wid = t >> 6;
#pragma unroll
  for (int o = 32; o > 0; o >>= 1) v += __shfl_down(v, o);
  __syncthreads();                 // protect scr across repeated calls
  if (lane == 0) scr[wid] = v;
  __syncthreads();
  return scr[0] + scr[1] + scr[2] + scr[3];
}

// ---------- dtype detection ----------
// flags[0]: mask element size code (0 = 4-byte, 1 = 1-byte, 2 = 2-byte)
// flags[1]: float dtype (1 = bf16, 0 = f32), probed from norm_f_w == ones
// Mask row 0 has exactly 256 true among 1024 elements; nonzero counts under
// the three views (each reading <= 4096 bytes, in-bounds for all layouts)
// discriminate uniquely.
__global__ void detect_kernel(const void* mask, const uint32_t* nf, int* flags) {
  __shared__ int cnt[3];
  int t = threadIdx.x;
  if (t < 3) cnt[t] = 0;
  __syncthreads();
  const uint32_t* pi = (const uint32_t*)mask;
  const uint16_t* ph = (const uint16_t*)mask;
  const uint8_t*  pb = (const uint8_t*)mask;
  int c32 = 0, cbf = 0, c8 = 0;
  for (int i = t; i < 1024; i += 256) {
    c32 += (pi[i] != 0u);
    cbf += (ph[i] != 0);
    c8  += (pb[i] != 0);
  }
  atomicAdd(&cnt[0], c32);
  atomicAdd(&cnt[1], cbf);
  atomicAdd(&cnt[2], c8);
  __syncthreads();
  if (t == 0) {
    int f;
    if (cnt[0] == 256) f = 0;
    else if (cnt[1] == 256) f = 2;
    else f = 1;
    flags[0] = f;
    flags[1] = (nf[0] == 0x3F800000u) ? 0 : 1;  // f32 ones vs bf16 ones pair
  }
}

// ---------- convert input (bf16 or f32) -> f32 workspace copy ----------
__global__ __launch_bounds__(256) void cvt_kernel(const void* __restrict__ src,
                                                  float* __restrict__ dst, int n,
                                                  const int* __restrict__ flags) {
  int i = blockIdx.x * 256 + threadIdx.x;
  if (i >= n) return;
  if (flags[1]) dst[i] = bs2f(((const uint16_t*)src)[i]);
  else          dst[i] = ((const float*)src)[i];
}

// ---------- visible-index compaction (stable) ----------
__global__ __launch_bounds__(1024) void order_kernel(const void* mask,
                                                     const int* __restrict__ flags,
                                                     int* __restrict__ order) {
  int b = blockIdx.x, i = threadIdx.x;
  int f = flags[0];
  int mv;
  if (f == 0)      mv = (((const uint32_t*)mask)[b * N_TOK + i] != 0u);
  else if (f == 1) mv = (((const uint8_t*)mask)[b * N_TOK + i] != 0);
  else             mv = (((const uint16_t*)mask)[b * N_TOK + i] != 0);
  int vis = !mv;
  unsigned long long mb = __ballot(vis);
  int lane = i & 63, wid = i >> 6;
  int wpre = __popcll(mb & ((1ull << lane) - 1ull));
  __shared__ int wsum[16];
  __shared__ int woff[16];
  if (lane == 0) wsum[wid] = __popcll(mb);
  __syncthreads();
  if (i == 0) { int a = 0; for (int w = 0; w < 16; ++w) { woff[w] = a; a += wsum[w]; } }
  __syncthreads();
  if (vis) {
    int pos = woff[wid] + wpre;
    if (pos < LVIS) order[b * LVIS + pos] = i;
  }
}

// ---------- gather tokens (f32), init hidden/residual ----------
__global__ __launch_bounds__(256) void gather_kernel(const float* __restrict__ tokens,
                                                     const int* __restrict__ order,
                                                     float* __restrict__ hidden,
                                                     float* __restrict__ residual) {
  int row = blockIdx.x;
  int b = row / LVIS;
  int d = threadIdx.x;
  int idx = order[row];
  float v = tokens[((size_t)(b * N_TOK + idx)) * DM + d];
  hidden[(size_t)row * DM + d] = v;
  residual[(size_t)row * DM + d] = 0.f;
}

// ---------- residual += hidden; rmsnorm -> out ----------
__global__ __launch_bounds__(256) void resid_rms_kernel(const float* __restrict__ hidden,
                                                        float* __restrict__ residual,
                                                        const float* __restrict__ nw,
                                                        float* __restrict__ out) {
  __shared__ float scr[4];
  int row = blockIdx.x, d = threadIdx.x;
  size_t i = (size_t)row * DM + d;
  float r = residual[i] + hidden[i];
  residual[i] = r;
  float ss = block_sum256(r * r, scr);
  out[i] = r * rsqrtf(ss / DM + EPS_F) * nw[d];
}

// ---------- f32 GEMM, C[M,N] = A[M,K] * W[N,K]^T ----------
__global__ __launch_bounds__(256) void gemm_kernel(const float* __restrict__ A,
                                                   const float* __restrict__ W,
                                                   float* __restrict__ C,
                                                   int M, int N, int K) {
  __shared__ float As[16][68];
  __shared__ float Ws[16][68];
  const int t = threadIdx.x;
  const int m0 = blockIdx.y * 64, n0 = blockIdx.x * 64;
  const int tr = t >> 2, tg = (t & 3) * 4;
  const int tm = (t >> 4) * 4, tn = (t & 15) * 4;
  float acc[4][4] = {{0.f}};
  for (int k0 = 0; k0 < K; k0 += 16) {
    float4 av = *(const float4*)(A + (size_t)(m0 + tr) * K + k0 + tg);
    float4 wv = make_float4(0.f, 0.f, 0.f, 0.f);
    int wr = n0 + tr;
    if (wr < N) wv = *(const float4*)(W + (size_t)wr * K + k0 + tg);
    As[tg + 0][tr] = av.x; As[tg + 1][tr] = av.y; As[tg + 2][tr] = av.z; As[tg + 3][tr] = av.w;
    Ws[tg + 0][tr] = wv.x; Ws[tg + 1][tr] = wv.y; Ws[tg + 2][tr] = wv.z; Ws[tg + 3][tr] = wv.w;
    __syncthreads();
#pragma unroll
    for (int k = 0; k < 16; ++k) {
      float4 a = *(const float4*)&As[k][tm];
      float4 b = *(const float4*)&Ws[k][tn];
      float aj[4] = {a.x, a.y, a.z, a.w};
      float bj[4] = {b.x, b.y, b.z, b.w};
#pragma unroll
      for (int x = 0; x < 4; ++x)
#pragma unroll
        for (int y = 0; y < 4; ++y) acc[x][y] += aj[x] * bj[y];
    }
    __syncthreads();
  }
#pragma unroll
  for (int x = 0; x < 4; ++x) {
    size_t crow = (size_t)(m0 + tm + x) * N;
    if (n0 + tn + 3 < N) {
      *(float4*)(C + crow + n0 + tn) = make_float4(acc[x][0], acc[x][1], acc[x][2], acc[x][3]);
    } else {
#pragma unroll
      for (int y = 0; y < 4; ++y)
        if (n0 + tn + y < N) C[crow + n0 + tn + y] = acc[x][y];
    }
  }
}

// ---------- depthwise conv(4) + bias + silu ----------
__global__ __launch_bounds__(256) void conv_silu_kernel(const float* __restrict__ xz,
                                                        const float* __restrict__ cw,
                                                        const float* __restrict__ cb,
                                                        float* __restrict__ xo) {
  int g = blockIdx.x * 256 + threadIdx.x;
  int d = g & (DIN - 1);
  int row = g >> 9;
  int l = row % LVIS;
  float4 w = *(const float4*)(cw + d * 4);
  float a = cb[d];
  const float* xc = xz + (size_t)row * 1024 + d;
  if (l >= 3) a += xc[-3 * 1024] * w.x;
  if (l >= 2) a += xc[-2 * 1024] * w.y;
  if (l >= 1) a += xc[-1 * 1024] * w.z;
  a += xc[0] * w.w;
  xo[g] = silu_f(a);
}

// ---------- dt = softplus(dtr @ dtw^T + dtb) ----------
__global__ __launch_bounds__(512) void dt_kernel(const float* __restrict__ xdbl,
                                                 const float* __restrict__ dtw,
                                                 const float* __restrict__ dtb,
                                                 float* __restrict__ dt) {
  __shared__ float r16[16];
  int row = blockIdx.x, d = threadIdx.x;
  if (d < 16) r16[d] = xdbl[(size_t)row * 48 + d];
  __syncthreads();
  const float4* wp = (const float4*)(dtw + d * 16);
  float4 w0 = wp[0], w1 = wp[1], w2 = wp[2], w3 = wp[3];
  float wv[16] = {w0.x, w0.y, w0.z, w0.w, w1.x, w1.y, w1.z, w1.w,
                  w2.x, w2.y, w2.z, w2.w, w3.x, w3.y, w3.z, w3.w};
  float a = dtb[d];
#pragma unroll
  for (int r = 0; r < 16; ++r) a += r16[r] * wv[r];
  float sp = fmaxf(a, 0.f) + log1pf(__expf(-fabsf(a)));
  dt[(size_t)row * DIN + d] = sp;
}

// ---------- selective scan: pass 1 (chunk-local scan + dA products) ----------
__global__ __launch_bounds__(256) void scan1_kernel(const float* __restrict__ dt,
                                                    const float* __restrict__ xb,
                                                    const float* __restrict__ xdbl,
                                                    const float* __restrict__ Alog,
                                                    float* __restrict__ hend,
                                                    float* __restrict__ pend) {
  int g = blockIdx.x * 256 + threadIdx.x;  // B_*NCHUNK*DIN = 65536
  int d = g & (DIN - 1);
  int c = (g >> 9) & (NCHUNK - 1);
  int b = g >> 14;
  float A[16];
  {
    const float4* ap = (const float4*)(Alog + (size_t)d * 16);
    float4 a0 = ap[0], a1 = ap[1], a2 = ap[2], a3 = ap[3];
    float tmp[16] = {a0.x, a0.y, a0.z, a0.w, a1.x, a1.y, a1.z, a1.w,
                     a2.x, a2.y, a2.z, a2.w, a3.x, a3.y, a3.z, a3.w};
#pragma unroll
    for (int s = 0; s < 16; ++s) A[s] = -__expf(tmp[s]);
  }
  float h[16], p[16];
#pragma unroll
  for (int s = 0; s < 16; ++s) { h[s] = 0.f; p[s] = 1.f; }
  size_t rowbase = (size_t)b * LVIS + (size_t)c * CLEN;
  for (int l = 0; l < CLEN; ++l) {
    size_t row = rowbase + l;
    float dtv = dt[row * DIN + d];
    float xv  = xb[row * DIN + d];
    float dtx = dtv * xv;
    const float4* Bp = (const float4*)(xdbl + row * 48 + 16);
    float4 b0 = Bp[0], b1 = Bp[1], b2 = Bp[2], b3 = Bp[3];
    float Bv[16] = {b0.x, b0.y, b0.z, b0.w, b1.x, b1.y, b1.z, b1.w,
                    b2.x, b2.y, b2.z, b2.w, b3.x, b3.y, b3.z, b3.w};
#pragma unroll
    for (int s = 0; s < 16; ++s) {
      float dA = __expf(dtv * A[s]);
      h[s] = dA * h[s] + dtx * Bv[s];
      p[s] *= dA;
    }
  }
  float4* hp = (float4*)(hend + (size_t)g * 16);
  float4* pp = (float4*)(pend + (size_t)g * 16);
#pragma unroll
  for (int q = 0; q < 4; ++q) {
    hp[q] = make_float4(h[4*q], h[4*q+1], h[4*q+2], h[4*q+3]);
    pp[q] = make_float4(p[4*q], p[4*q+1], p[4*q+2], p[4*q+3]);
  }
}

// ---------- pass 2: serial carry across chunks ----------
__global__ __launch_bounds__(256) void scan2_kernel(const float* __restrict__ hend,
                                                    const float* __restrict__ pend,
                                                    float* __restrict__ hin) {
  int g = blockIdx.x * 256 + threadIdx.x;  // B_*DIN*16 = 32768
  int s = g & 15;
  int d = (g >> 4) & (DIN - 1);
  int b = g >> 13;
  float h = 0.f;
  for (int c = 0; c < NCHUNK; ++c) {
    size_t idx = (((size_t)(b * NCHUNK + c) * DIN + d)) * 16 + s;
    hin[idx] = h;
    h = pend[idx] * h + hend[idx];
  }
}

// ---------- pass 3: recompute with carry, emit y = (scan + D*x) * silu(z) ----------
__global__ __launch_bounds__(256) void scan3_kernel(const float* __restrict__ dt,
                                                    const float* __restrict__ xb,
                                                    const float* __restrict__ xdbl,
                                                    const float* __restrict__ xz,
                                                    const float* __restrict__ Alog,
                                                    const float* __restrict__ Dskip,
                                                    const float* __restrict__ hin,
                                                    float* __restrict__ ymul) {
  int g = blockIdx.x * 256 + threadIdx.x;
  int d = g & (DIN - 1);
  int c = (g >> 9) & (NCHUNK - 1);
  int b = g >> 14;
  float A[16];
  {
    const float4* ap = (const float4*)(Alog + (size_t)d * 16);
    float4 a0 = ap[0], a1 = ap[1], a2 = ap[2], a3 = ap[3];
    float tmp[16] = {a0.x, a0.y, a0.z, a0.w, a1.x, a1.y, a1.z, a1.w,
                     a2.x, a2.y, a2.z, a2.w, a3.x, a3.y, a3.z, a3.w};
#pragma unroll
    for (int s = 0; s < 16; ++s) A[s] = -__expf(tmp[s]);
  }
  float h[16];
  {
    const float4* ip = (const float4*)(hin + (size_t)g * 16);
    float4 h0 = ip[0], h1 = ip[1], h2 = ip[2], h3 = ip[3];
    h[0]=h0.x; h[1]=h0.y; h[2]=h0.z; h[3]=h0.w;
    h[4]=h1.x; h[5]=h1.y; h[6]=h1.z; h[7]=h1.w;
    h[8]=h2.x; h[9]=h2.y; h[10]=h2.z; h[11]=h2.w;
    h[12]=h3.x; h[13]=h3.y; h[14]=h3.z; h[15]=h3.w;
  }
  float Dv = Dskip[d];
  size_t rowbase = (size_t)b * LVIS + (size_t)c * CLEN;
  for (int l = 0; l < CLEN; ++l) {
    size_t row = rowbase + l;
    float dtv = dt[row * DIN + d];
    float xv  = xb[row * DIN + d];
    float dtx = dtv * xv;
    const float4* Bp = (const float4*)(xdbl + row * 48 + 16);
    float4 b0 = Bp[0], b1 = Bp[1], b2 = Bp[2], b3 = Bp[3];
    const float4* Cp = (const float4*)(xdbl + row * 48 + 32);
    float4 c0 = Cp[0], c1 = Cp[1], c2 = Cp[2], c3 = Cp[3];
    float Bv[16] = {b0.x, b0.y, b0.z, b0.w, b1.x, b1.y, b1.z, b1.w,
                    b2.x, b2.y, b2.z, b2.w, b3.x, b3.y, b3.z, b3.w};
    float Cv[16] = {c0.x, c0.y, c0.z, c0.w, c1.x, c1.y, c1.z, c1.w,
                    c2.x, c2.y, c2.z, c2.w, c3.x, c3.y, c3.z, c3.w};
    float y = 0.f;
#pragma unroll
    for (int s = 0; s < 16; ++s) {
      float dA = __expf(dtv * A[s]);
      h[s] = dA * h[s] + dtx * Bv[s];
      y += h[s] * Cv[s];
    }
    float zv = xz[row * 1024 + 512 + d];
    ymul[row * DIN + d] = (y + Dv * xv) * silu_f(zv);
  }
}

// ---------- final: rmsnorm(h + r) -> layernorm -> out (flag-typed) ----------
__global__ __launch_bounds__(256) void final_kernel(const float* __restrict__ hidden,
                                                    const float* __restrict__ residual,
                                                    const float* __restrict__ nfw,
                                                    const float* __restrict__ lnw,
                                                    const float* __restrict__ lnb,
                                                    const int* __restrict__ flags,
                                                    void* __restrict__ out) {
  __shared__ float scr[4];
  int row = blockIdx.x, d = threadIdx.x;
  size_t i = (size_t)row * DM + d;
  float v = hidden[i] + residual[i];
  float ss = block_sum256(v * v, scr);
  float h = v * rsqrtf(ss / DM + EPS_F) * nfw[d];
  float mu = block_sum256(h, scr) / DM;
  float dv = h - mu;
  float var = block_sum256(dv * dv, scr) / DM;
  float o = dv * rsqrtf(var + EPS_F) * lnw[d] + lnb[d];
  int b = row / LVIS, l = row % LVIS;
  size_t oi = (l < LVIS - 1)
                ? ((size_t)(b * (LVIS - 1) + l) * DM + d)
                : ((size_t)B_ * (LVIS - 1) * DM + (size_t)b * DM + d);
  if (flags[1]) ((uint16_t*)out)[oi] = f2b(o);
  else          ((float*)out)[oi] = o;
}

// ---------- host ----------
extern "C" void kernel_launch(void* const* d_in, const int* in_sizes, int n_in,
                              void* d_out, int out_size, void* d_ws, size_t ws_size,
                              hipStream_t stream) {
  char* ws = (char*)d_ws;
  size_t off = 0;
  auto alloc = [&](size_t bytes) -> void* {
    void* p = ws + off;
    off += (bytes + 255) & ~(size_t)255;
    return p;
  };
  // f32 copies of float inputs (indices per setup_inputs order; 1 = mask, skipped)
  float* fin[15];
  for (int i = 0; i < 15; ++i) {
    if (i == 1) { fin[i] = nullptr; continue; }
    fin[i] = (float*)alloc((size_t)in_sizes[i] * 4);
  }
  float* hidden   = (float*)alloc((size_t)MROWS * DM * 4);
  float* residual = (float*)alloc((size_t)MROWS * DM * 4);
  float* rmsb     = (float*)alloc((size_t)MROWS * DM * 4);
  float* xz       = (float*)alloc((size_t)MROWS * 1024 * 4);
  float* xb       = (float*)alloc((size_t)MROWS * DIN * 4);
  float* xdbl     = (float*)alloc((size_t)MROWS * 48 * 4);
  float* dtbuf    = (float*)alloc((size_t)MROWS * DIN * 4);
  float* ymul     = (float*)alloc((size_t)MROWS * DIN * 4);
  float* hend     = (float*)alloc((size_t)B_ * NCHUNK * DIN * 16 * 4);
  float* pend     = (float*)alloc((size_t)B_ * NCHUNK * DIN * 16 * 4);
  float* hin      = (float*)alloc((size_t)B_ * NCHUNK * DIN * 16 * 4);
  int*   order    = (int*)alloc((size_t)B_ * LVIS * 4);
  int*   flags    = (int*)alloc(256);

  detect_kernel<<<1, 256, 0, stream>>>(d_in[1], (const uint32_t*)d_in[12], flags);
  for (int i = 0; i < 15; ++i) {
    if (i == 1) continue;
    int n = in_sizes[i];
    cvt_kernel<<<(n + 255) / 256, 256, 0, stream>>>(d_in[i], fin[i], n, flags);
  }
  const float* tokens = fin[0];
  const float* in_w   = fin[2];
  const float* conv_w = fin[3];
  const float* conv_b = fin[4];
  const float* x_w    = fin[5];
  const float* dt_w   = fin[6];
  const float* dt_b   = fin[7];
  const float* A_log  = fin[8];
  const float* D_skip = fin[9];
  const float* out_w  = fin[10];
  const float* norm_w = fin[11];
  const float* norm_f = fin[12];
  const float* ln_w   = fin[13];
  const float* ln_b   = fin[14];

  order_kernel<<<B_, 1024, 0, stream>>>(d_in[1], flags, order);
  gather_kernel<<<MROWS, 256, 0, stream>>>(tokens, order, hidden, residual);

  for (int L = 0; L < DEPTH; ++L) {
    resid_rms_kernel<<<MROWS, 256, 0, stream>>>(hidden, residual, norm_w + (size_t)L * DM, rmsb);
    gemm_kernel<<<dim3(1024 / 64, MROWS / 64), 256, 0, stream>>>(
        rmsb, in_w + (size_t)L * 1024 * DM, xz, MROWS, 1024, DM);
    conv_silu_kernel<<<(MROWS * DIN) / 256, 256, 0, stream>>>(
        xz, conv_w + (size_t)L * DIN * 4, conv_b + (size_t)L * DIN, xb);
    gemm_kernel<<<dim3(1, MROWS / 64), 256, 0, stream>>>(
        xb, x_w + (size_t)L * 48 * DIN, xdbl, MROWS, 48, DIN);
    dt_kernel<<<MROWS, 512, 0, stream>>>(
        xdbl, dt_w + (size_t)L * DIN * 16, dt_b + (size_t)L * DIN, dtbuf);
    scan1_kernel<<<(B_ * NCHUNK * DIN) / 256, 256, 0, stream>>>(
        dtbuf, xb, xdbl, A_log + (size_t)L * DIN * 16, hend, pend);
    scan2_kernel<<<(B_ * DIN * 16) / 256, 256, 0, stream>>>(hend, pend, hin);
    scan3_kernel<<<(B_ * NCHUNK * DIN) / 256, 256, 0, stream>>>(
        dtbuf, xb, xdbl, xz, A_log + (size_t)L * DIN * 16, D_skip + (size_t)L * DIN, hin, ymul);
    gemm_kernel<<<dim3(DM / 64, MROWS / 64), 256, 0, stream>>>(
        ymul, out_w + (size_t)L * DM * DIN, hidden, MROWS, DM, DIN);
  }

  final_kernel<<<MROWS, 256, 0, stream>>>(hidden, residual, norm_f, ln_w, ln_b,
                                          flags, d_out);
}

// Round 3
// 1640.090 us; speedup vs baseline: 1.2512x; 1.2512x over previous
//
#include <hip/hip_runtime.h>
#include <stdint.h>

#define B_ 4
#define N_TOK 1024
#define DM 256
#define DEPTH 12
#define DSTATE 16
#define DIN 512
#define LVIS 768
#define MROWS (B_ * LVIS)  // 3072
#define NCHUNK 32
#define CLEN 24            // 768 / 32
#define EPS_F 1e-5f

typedef __attribute__((ext_vector_type(8))) short s8v;   // 8 bf16 (4 VGPRs)
typedef __attribute__((ext_vector_type(4))) float f4v;   // 4 f32 acc

// ---------- helpers ----------
__device__ __forceinline__ float bs2f(uint32_t u) {
  uint32_t x = (u & 0xffffu) << 16;
  float f; __builtin_memcpy(&f, &x, 4); return f;
}
__device__ __forceinline__ uint16_t f2b(float f) {
  uint32_t u; __builtin_memcpy(&u, &f, 4);
  return (uint16_t)((u + 0x7fffu + ((u >> 16) & 1u)) >> 16);
}
__device__ __forceinline__ float silu_f(float x) { return x / (1.f + __expf(-x)); }
__device__ __forceinline__ float block_sum256(float v, volatile float* scr) {
  int t = threadIdx.x, lane = t & 63, wid = t >> 6;
#pragma unroll
  for (int o = 32; o > 0; o >>= 1) v += __shfl_down(v, o);
  __syncthreads();
  if (lane == 0) scr[wid] = v;
  __syncthreads();
  return scr[0] + scr[1] + scr[2] + scr[3];
}

// ---------- dtype detection ----------
// flags[0]: mask element size code (0 = 4-byte, 1 = 1-byte, 2 = 2-byte)
// flags[1]: float dtype (1 = bf16, 0 = f32), probed from norm_f_w == ones
__global__ void detect_kernel(const void* mask, const uint32_t* nf, int* flags) {
  __shared__ int cnt[3];
  int t = threadIdx.x;
  if (t < 3) cnt[t] = 0;
  __syncthreads();
  const uint32_t* pi = (const uint32_t*)mask;
  const uint16_t* ph = (const uint16_t*)mask;
  const uint8_t*  pb = (const uint8_t*)mask;
  int c32 = 0, cbf = 0, c8 = 0;
  for (int i = t; i < 1024; i += 256) {
    c32 += (pi[i] != 0u);
    cbf += (ph[i] != 0);
    c8  += (pb[i] != 0);
  }
  atomicAdd(&cnt[0], c32);
  atomicAdd(&cnt[1], cbf);
  atomicAdd(&cnt[2], c8);
  __syncthreads();
  if (t == 0) {
    int f;
    if (cnt[0] == 256) f = 0;
    else if (cnt[1] == 256) f = 2;
    else f = 1;
    flags[0] = f;
    flags[1] = (nf[0] == 0x3F800000u) ? 0 : 1;
  }
}

// ---------- convert input -> f32 copy ----------
__global__ __launch_bounds__(256) void cvt_kernel(const void* __restrict__ src,
                                                  float* __restrict__ dst, int n,
                                                  const int* __restrict__ flags) {
  int i = blockIdx.x * 256 + threadIdx.x;
  if (i >= n) return;
  if (flags[1]) dst[i] = bs2f(((const uint16_t*)src)[i]);
  else          dst[i] = ((const float*)src)[i];
}

// ---------- convert input -> bf16 copy (for MFMA weights) ----------
__global__ __launch_bounds__(256) void cvt16_kernel(const void* __restrict__ src,
                                                    uint16_t* __restrict__ dst, int n,
                                                    const int* __restrict__ flags) {
  int i = blockIdx.x * 256 + threadIdx.x;
  if (i >= n) return;
  if (flags[1]) dst[i] = ((const uint16_t*)src)[i];
  else          dst[i] = f2b(((const float*)src)[i]);
}

// ---------- visible-index compaction (stable) ----------
__global__ __launch_bounds__(1024) void order_kernel(const void* mask,
                                                     const int* __restrict__ flags,
                                                     int* __restrict__ order) {
  int b = blockIdx.x, i = threadIdx.x;
  int f = flags[0];
  int mv;
  if (f == 0)      mv = (((const uint32_t*)mask)[b * N_TOK + i] != 0u);
  else if (f == 1) mv = (((const uint8_t*)mask)[b * N_TOK + i] != 0);
  else             mv = (((const uint16_t*)mask)[b * N_TOK + i] != 0);
  int vis = !mv;
  unsigned long long mb = __ballot(vis);
  int lane = i & 63, wid = i >> 6;
  int wpre = __popcll(mb & ((1ull << lane) - 1ull));
  __shared__ int wsum[16];
  __shared__ int woff[16];
  if (lane == 0) wsum[wid] = __popcll(mb);
  __syncthreads();
  if (i == 0) { int a = 0; for (int w = 0; w < 16; ++w) { woff[w] = a; a += wsum[w]; } }
  __syncthreads();
  if (vis) {
    int pos = woff[wid] + wpre;
    if (pos < LVIS) order[b * LVIS + pos] = i;
  }
}

// ---------- gather tokens, init hidden/residual ----------
__global__ __launch_bounds__(256) void gather_kernel(const void* __restrict__ tokens,
                                                     const int* __restrict__ order,
                                                     const int* __restrict__ flags,
                                                     float* __restrict__ hidden,
                                                     float* __restrict__ residual) {
  int row = blockIdx.x;
  int b = row / LVIS;
  int d = threadIdx.x;
  int idx = order[row];
  size_t src = ((size_t)(b * N_TOK + idx)) * DM + d;
  float v = flags[1] ? bs2f(((const uint16_t*)tokens)[src]) : ((const float*)tokens)[src];
  hidden[(size_t)row * DM + d] = v;
  residual[(size_t)row * DM + d] = 0.f;
}

// ---------- residual += hidden; rmsnorm -> bf16 out ----------
__global__ __launch_bounds__(256) void resid_rms_kernel(const float* __restrict__ hidden,
                                                        float* __restrict__ residual,
                                                        const float* __restrict__ nw,
                                                        uint16_t* __restrict__ out16) {
  __shared__ float scr[4];
  int row = blockIdx.x, d = threadIdx.x;
  size_t i = (size_t)row * DM + d;
  float r = residual[i] + hidden[i];
  residual[i] = r;
  float ss = block_sum256(r * r, scr);
  out16[i] = f2b(r * rsqrtf(ss / DM + EPS_F) * nw[d]);
}

// ---------- MFMA bf16 GEMM: C[M,N] = A[M,K] * W[N,K]^T, f32 out ----------
// block = 4 waves, 64x64 tile. Wave w: rows m0+16w..m0+16w+15, 4 n-tiles of 16.
// A/B frag: [m|n = lane&15][k = (lane>>4)*8 + j]; D: col=lane&15, row=(lane>>4)*4+r.
__global__ __launch_bounds__(256) void mfma_gemm_kernel(const uint16_t* __restrict__ A,
                                                        const uint16_t* __restrict__ W,
                                                        float* __restrict__ C,
                                                        int M, int N, int K) {
  const int t = threadIdx.x;
  const int wv = t >> 6, lane = t & 63;
  const int lm = lane & 15, lq = lane >> 4;
  const int m0 = blockIdx.y * 64 + wv * 16;
  const int n0 = blockIdx.x * 64;
  f4v acc[4];
#pragma unroll
  for (int j = 0; j < 4; ++j) acc[j] = (f4v){0.f, 0.f, 0.f, 0.f};
  const uint16_t* arow = A + (size_t)(m0 + lm) * K + lq * 8;
  for (int k0 = 0; k0 < K; k0 += 32) {
    s8v a = *(const s8v*)(arow + k0);
#pragma unroll
    for (int j = 0; j < 4; ++j) {
      int n = n0 + j * 16 + lm;
      s8v b = (s8v){0, 0, 0, 0, 0, 0, 0, 0};
      if (n < N) b = *(const s8v*)(W + (size_t)n * K + lq * 8 + k0);
      acc[j] = __builtin_amdgcn_mfma_f32_16x16x32_bf16(a, b, acc[j], 0, 0, 0);
    }
  }
#pragma unroll
  for (int j = 0; j < 4; ++j) {
    int col = n0 + j * 16 + lm;
    if (col < N) {
#pragma unroll
      for (int r = 0; r < 4; ++r) {
        int row = m0 + lq * 4 + r;
        C[(size_t)row * N + col] = acc[j][r];
      }
    }
  }
}

// ---------- depthwise conv(4) + bias + silu; emits f32 (scan) + bf16 (x_proj) ----------
__global__ __launch_bounds__(256) void conv_silu_kernel(const float* __restrict__ xz,
                                                        const float* __restrict__ cw,
                                                        const float* __restrict__ cb,
                                                        float* __restrict__ xo,
                                                        uint16_t* __restrict__ xo16) {
  int g = blockIdx.x * 256 + threadIdx.x;
  int d = g & (DIN - 1);
  int row = g >> 9;
  int l = row % LVIS;
  float4 w = *(const float4*)(cw + d * 4);
  float a = cb[d];
  const float* xc = xz + (size_t)row * 1024 + d;
  if (l >= 3) a += xc[-3 * 1024] * w.x;
  if (l >= 2) a += xc[-2 * 1024] * w.y;
  if (l >= 1) a += xc[-1 * 1024] * w.z;
  a += xc[0] * w.w;
  float s = silu_f(a);
  xo[g] = s;
  xo16[g] = f2b(s);
}

// ---------- dt = softplus(dtr @ dtw^T + dtb) ----------
__global__ __launch_bounds__(512) void dt_kernel(const float* __restrict__ xdbl,
                                                 const float* __restrict__ dtw,
                                                 const float* __restrict__ dtb,
                                                 float* __restrict__ dt) {
  __shared__ float r16[16];
  int row = blockIdx.x, d = threadIdx.x;
  if (d < 16) r16[d] = xdbl[(size_t)row * 48 + d];
  __syncthreads();
  const float4* wp = (const float4*)(dtw + d * 16);
  float4 w0 = wp[0], w1 = wp[1], w2 = wp[2], w3 = wp[3];
  float wv[16] = {w0.x, w0.y, w0.z, w0.w, w1.x, w1.y, w1.z, w1.w,
                  w2.x, w2.y, w2.z, w2.w, w3.x, w3.y, w3.z, w3.w};
  float a = dtb[d];
#pragma unroll
  for (int r = 0; r < 16; ++r) a += r16[r] * wv[r];
  float sp = fmaxf(a, 0.f) + log1pf(__expf(-fabsf(a)));
  dt[(size_t)row * DIN + d] = sp;
}

// ---------- selective scan: pass 1 (chunk-local scan + dA products) ----------
__global__ __launch_bounds__(256) void scan1_kernel(const float* __restrict__ dt,
                                                    const float* __restrict__ xb,
                                                    const float* __restrict__ xdbl,
                                                    const float* __restrict__ Alog,
                                                    float* __restrict__ hend,
                                                    float* __restrict__ pend) {
  int g = blockIdx.x * 256 + threadIdx.x;  // B_*NCHUNK*DIN = 65536
  int d = g & (DIN - 1);
  int c = (g >> 9) & (NCHUNK - 1);
  int b = g >> 14;
  float A[16];
  {
    const float4* ap = (const float4*)(Alog + (size_t)d * 16);
    float4 a0 = ap[0], a1 = ap[1], a2 = ap[2], a3 = ap[3];
    float tmp[16] = {a0.x, a0.y, a0.z, a0.w, a1.x, a1.y, a1.z, a1.w,
                     a2.x, a2.y, a2.z, a2.w, a3.x, a3.y, a3.z, a3.w};
#pragma unroll
    for (int s = 0; s < 16; ++s) A[s] = -__expf(tmp[s]);
  }
  float h[16], p[16];
#pragma unroll
  for (int s = 0; s < 16; ++s) { h[s] = 0.f; p[s] = 1.f; }
  size_t rowbase = (size_t)b * LVIS + (size_t)c * CLEN;
  for (int l = 0; l < CLEN; ++l) {
    size_t row = rowbase + l;
    float dtv = dt[row * DIN + d];
    float xv  = xb[row * DIN + d];
    float dtx = dtv * xv;
    const float4* Bp = (const float4*)(xdbl + row * 48 + 16);
    float4 b0 = Bp[0], b1 = Bp[1], b2 = Bp[2], b3 = Bp[3];
    float Bv[16] = {b0.x, b0.y, b0.z, b0.w, b1.x, b1.y, b1.z, b1.w,
                    b2.x, b2.y, b2.z, b2.w, b3.x, b3.y, b3.z, b3.w};
#pragma unroll
    for (int s = 0; s < 16; ++s) {
      float dA = __expf(dtv * A[s]);
      h[s] = dA * h[s] + dtx * Bv[s];
      p[s] *= dA;
    }
  }
  float4* hp = (float4*)(hend + (size_t)g * 16);
  float4* pp = (float4*)(pend + (size_t)g * 16);
#pragma unroll
  for (int q = 0; q < 4; ++q) {
    hp[q] = make_float4(h[4*q], h[4*q+1], h[4*q+2], h[4*q+3]);
    pp[q] = make_float4(p[4*q], p[4*q+1], p[4*q+2], p[4*q+3]);
  }
}

// ---------- pass 2: serial carry across chunks ----------
__global__ __launch_bounds__(256) void scan2_kernel(const float* __restrict__ hend,
                                                    const float* __restrict__ pend,
                                                    float* __restrict__ hin) {
  int g = blockIdx.x * 256 + threadIdx.x;  // B_*DIN*16 = 32768
  int s = g & 15;
  int d = (g >> 4) & (DIN - 1);
  int b = g >> 13;
  float h = 0.f;
  for (int c = 0; c < NCHUNK; ++c) {
    size_t idx = (((size_t)(b * NCHUNK + c) * DIN + d)) * 16 + s;
    hin[idx] = h;
    h = pend[idx] * h + hend[idx];
  }
}

// ---------- pass 3: recompute with carry, emit y*silu(z) as bf16 ----------
__global__ __launch_bounds__(256) void scan3_kernel(const float* __restrict__ dt,
                                                    const float* __restrict__ xb,
                                                    const float* __restrict__ xdbl,
                                                    const float* __restrict__ xz,
                                                    const float* __restrict__ Alog,
                                                    const float* __restrict__ Dskip,
                                                    const float* __restrict__ hin,
                                                    uint16_t* __restrict__ ymul16) {
  int g = blockIdx.x * 256 + threadIdx.x;
  int d = g & (DIN - 1);
  int c = (g >> 9) & (NCHUNK - 1);
  int b = g >> 14;
  float A[16];
  {
    const float4* ap = (const float4*)(Alog + (size_t)d * 16);
    float4 a0 = ap[0], a1 = ap[1], a2 = ap[2], a3 = ap[3];
    float tmp[16] = {a0.x, a0.y, a0.z, a0.w, a1.x, a1.y, a1.z, a1.w,
                     a2.x, a2.y, a2.z, a2.w, a3.x, a3.y, a3.z, a3.w};
#pragma unroll
    for (int s = 0; s < 16; ++s) A[s] = -__expf(tmp[s]);
  }
  float h[16];
  {
    const float4* ip = (const float4*)(hin + (size_t)g * 16);
    float4 h0 = ip[0], h1 = ip[1], h2 = ip[2], h3 = ip[3];
    h[0]=h0.x; h[1]=h0.y; h[2]=h0.z; h[3]=h0.w;
    h[4]=h1.x; h[5]=h1.y; h[6]=h1.z; h[7]=h1.w;
    h[8]=h2.x; h[9]=h2.y; h[10]=h2.z; h[11]=h2.w;
    h[12]=h3.x; h[13]=h3.y; h[14]=h3.z; h[15]=h3.w;
  }
  float Dv = Dskip[d];
  size_t rowbase = (size_t)b * LVIS + (size_t)c * CLEN;
  for (int l = 0; l < CLEN; ++l) {
    size_t row = rowbase + l;
    float dtv = dt[row * DIN + d];
    float xv  = xb[row * DIN + d];
    float dtx = dtv * xv;
    const float4* Bp = (const float4*)(xdbl + row * 48 + 16);
    float4 b0 = Bp[0], b1 = Bp[1], b2 = Bp[2], b3 = Bp[3];
    const float4* Cp = (const float4*)(xdbl + row * 48 + 32);
    float4 c0 = Cp[0], c1 = Cp[1], c2 = Cp[2], c3 = Cp[3];
    float Bv[16] = {b0.x, b0.y, b0.z, b0.w, b1.x, b1.y, b1.z, b1.w,
                    b2.x, b2.y, b2.z, b2.w, b3.x, b3.y, b3.z, b3.w};
    float Cv[16] = {c0.x, c0.y, c0.z, c0.w, c1.x, c1.y, c1.z, c1.w,
                    c2.x, c2.y, c2.z, c2.w, c3.x, c3.y, c3.z, c3.w};
    float y = 0.f;
#pragma unroll
    for (int s = 0; s < 16; ++s) {
      float dA = __expf(dtv * A[s]);
      h[s] = dA * h[s] + dtx * Bv[s];
      y += h[s] * Cv[s];
    }
    float zv = xz[row * 1024 + 512 + d];
    ymul16[row * DIN + d] = f2b((y + Dv * xv) * silu_f(zv));
  }
}

// ---------- final: rmsnorm(h + r) -> layernorm -> out (flag-typed) ----------
__global__ __launch_bounds__(256) void final_kernel(const float* __restrict__ hidden,
                                                    const float* __restrict__ residual,
                                                    const float* __restrict__ nfw,
                                                    const float* __restrict__ lnw,
                                                    const float* __restrict__ lnb,
                                                    const int* __restrict__ flags,
                                                    void* __restrict__ out) {
  __shared__ float scr[4];
  int row = blockIdx.x, d = threadIdx.x;
  size_t i = (size_t)row * DM + d;
  float v = hidden[i] + residual[i];
  float ss = block_sum256(v * v, scr);
  float h = v * rsqrtf(ss / DM + EPS_F) * nfw[d];
  float mu = block_sum256(h, scr) / DM;
  float dv = h - mu;
  float var = block_sum256(dv * dv, scr) / DM;
  float o = dv * rsqrtf(var + EPS_F) * lnw[d] + lnb[d];
  int b = row / LVIS, l = row % LVIS;
  size_t oi = (l < LVIS - 1)
                ? ((size_t)(b * (LVIS - 1) + l) * DM + d)
                : ((size_t)B_ * (LVIS - 1) * DM + (size_t)b * DM + d);
  if (flags[1]) ((uint16_t*)out)[oi] = f2b(o);
  else          ((float*)out)[oi] = o;
}

// ---------- host ----------
extern "C" void kernel_launch(void* const* d_in, const int* in_sizes, int n_in,
                              void* d_out, int out_size, void* d_ws, size_t ws_size,
                              hipStream_t stream) {
  char* ws = (char*)d_ws;
  size_t off = 0;
  auto alloc = [&](size_t bytes) -> void* {
    void* p = ws + off;
    off += (bytes + 255) & ~(size_t)255;
    return p;
  };
  // f32 copies for scalar-consumed float inputs
  // indices: 3 conv_w, 4 conv_b, 6 dt_w, 7 dt_b, 8 A_log, 9 D_skip, 11 norm_w,
  //          12 norm_f, 13 ln_w, 14 ln_b
  const int f32_idx[10] = {3, 4, 6, 7, 8, 9, 11, 12, 13, 14};
  float* f32c[15] = {nullptr};
  for (int j = 0; j < 10; ++j) {
    int i = f32_idx[j];
    f32c[i] = (float*)alloc((size_t)in_sizes[i] * 4);
  }
  // bf16 copies for MFMA weights: 2 in_proj_w, 5 x_proj_w, 10 out_proj_w
  const int b16_idx[3] = {2, 5, 10};
  uint16_t* b16c[15] = {nullptr};
  for (int j = 0; j < 3; ++j) {
    int i = b16_idx[j];
    b16c[i] = (uint16_t*)alloc((size_t)in_sizes[i] * 2);
  }
  float*    hidden   = (float*)alloc((size_t)MROWS * DM * 4);
  float*    residual = (float*)alloc((size_t)MROWS * DM * 4);
  uint16_t* rmsb16   = (uint16_t*)alloc((size_t)MROWS * DM * 2);
  float*    xz       = (float*)alloc((size_t)MROWS * 1024 * 4);
  float*    xb       = (float*)alloc((size_t)MROWS * DIN * 4);
  uint16_t* xb16     = (uint16_t*)alloc((size_t)MROWS * DIN * 2);
  float*    xdbl     = (float*)alloc((size_t)MROWS * 48 * 4);
  float*    dtbuf    = (float*)alloc((size_t)MROWS * DIN * 4);
  uint16_t* ymul16   = (uint16_t*)alloc((size_t)MROWS * DIN * 2);
  float*    hend     = (float*)alloc((size_t)B_ * NCHUNK * DIN * 16 * 4);
  float*    pend     = (float*)alloc((size_t)B_ * NCHUNK * DIN * 16 * 4);
  float*    hin      = (float*)alloc((size_t)B_ * NCHUNK * DIN * 16 * 4);
  int*      order    = (int*)alloc((size_t)B_ * LVIS * 4);
  int*      flags    = (int*)alloc(256);

  detect_kernel<<<1, 256, 0, stream>>>(d_in[1], (const uint32_t*)d_in[12], flags);
  for (int j = 0; j < 10; ++j) {
    int i = f32_idx[j];
    int n = in_sizes[i];
    cvt_kernel<<<(n + 255) / 256, 256, 0, stream>>>(d_in[i], f32c[i], n, flags);
  }
  for (int j = 0; j < 3; ++j) {
    int i = b16_idx[j];
    int n = in_sizes[i];
    cvt16_kernel<<<(n + 255) / 256, 256, 0, stream>>>(d_in[i], b16c[i], n, flags);
  }
  const uint16_t* in_w   = b16c[2];
  const float*    conv_w = f32c[3];
  const float*    conv_b = f32c[4];
  const uint16_t* x_w    = b16c[5];
  const float*    dt_w   = f32c[6];
  const float*    dt_b   = f32c[7];
  const float*    A_log  = f32c[8];
  const float*    D_skip = f32c[9];
  const uint16_t* out_w  = b16c[10];
  const float*    norm_w = f32c[11];
  const float*    norm_f = f32c[12];
  const float*    ln_w   = f32c[13];
  const float*    ln_b   = f32c[14];

  order_kernel<<<B_, 1024, 0, stream>>>(d_in[1], flags, order);
  gather_kernel<<<MROWS, 256, 0, stream>>>(d_in[0], order, flags, hidden, residual);

  for (int L = 0; L < DEPTH; ++L) {
    resid_rms_kernel<<<MROWS, 256, 0, stream>>>(hidden, residual,
                                                norm_w + (size_t)L * DM, rmsb16);
    mfma_gemm_kernel<<<dim3(1024 / 64, MROWS / 64), 256, 0, stream>>>(
        rmsb16, in_w + (size_t)L * 1024 * DM, xz, MROWS, 1024, DM);
    conv_silu_kernel<<<(MROWS * DIN) / 256, 256, 0, stream>>>(
        xz, conv_w + (size_t)L * DIN * 4, conv_b + (size_t)L * DIN, xb, xb16);
    mfma_gemm_kernel<<<dim3(1, MROWS / 64), 256, 0, stream>>>(
        xb16, x_w + (size_t)L * 48 * DIN, xdbl, MROWS, 48, DIN);
    dt_kernel<<<MROWS, 512, 0, stream>>>(
        xdbl, dt_w + (size_t)L * DIN * 16, dt_b + (size_t)L * DIN, dtbuf);
    scan1_kernel<<<(B_ * NCHUNK * DIN) / 256, 256, 0, stream>>>(
        dtbuf, xb, xdbl, A_log + (size_t)L * DIN * 16, hend, pend);
    scan2_kernel<<<(B_ * DIN * 16) / 256, 256, 0, stream>>>(hend, pend, hin);
    scan3_kernel<<<(B_ * NCHUNK * DIN) / 256, 256, 0, stream>>>(
        dtbuf, xb, xdbl, xz, A_log + (size_t)L * DIN * 16, D_skip + (size_t)L * DIN,
        hin, ymul16);
    mfma_gemm_kernel<<<dim3(DM / 64, MROWS / 64), 256, 0, stream>>>(
        ymul16, out_w + (size_t)L * DM * DIN, hidden, MROWS, DM, DIN);
  }

  final_kernel<<<MROWS, 256, 0, stream>>>(hidden, residual, norm_f, ln_w, ln_b,
                                          flags, d_out);
}